// Round 18
// baseline (204.943 us; speedup 1.0000x reference)
//
#include <hip/hip_runtime.h>
#include <hip/hip_bf16.h>
#include <math.h>

#define HW 2304
#define EPSV 1e-5f
#define INV_N (1.f / 294912.f)
// ATT_SCALE * log2(e): softmax runs in exp2 domain
#define QS_LOG2E (0.17677669529663687f * 1.44269504088896340f)
#define NSPLIT 4
// fixed exp2-domain softmax reference: scores are GN-normalized (sigma~1.5,
// max ~10); safe headroom to ~110. Cancels exactly in normalization.
#define MFIX 12.0f

enum { E_CV1 = 0, E_QKV = 1 };

typedef __attribute__((ext_vector_type(8))) short bf16x8;
typedef __attribute__((ext_vector_type(4))) float f32x4;

static __device__ __forceinline__ ushort b16(float f) {
    union { __hip_bfloat16 h; ushort u; } cv;
    cv.h = __float2bfloat16(f);
    return cv.u;
}
static __device__ __forceinline__ float bf(ushort u) {
    union { unsigned u; float f; } c; c.u = (unsigned)u << 16; return c.f;
}
// wave-reduce then 2 atomicAdds into STAT slot
static __device__ __forceinline__ void stat_acc(float* STAT, int slot, int b,
                                                float s, float sq) {
    #pragma unroll
    for (int off = 32; off; off >>= 1) { s += __shfl_xor(s, off); sq += __shfl_xor(sq, off); }
    if ((threadIdx.x & 63) == 0) {
        atomicAdd(&STAT[(slot * 3 + b) * 2], s);
        atomicAdd(&STAT[(slot * 3 + b) * 2 + 1], sq);
    }
}

// ---- prep: weight cvt + GN-fold (wave-parallel) + x transpose + STAT zero ----
__global__ __launch_bounds__(256) void prep(
    const float* __restrict__ cv1w, const float* __restrict__ projw,
    const float* __restrict__ f2w, const float* __restrict__ cv2w,
    const float* __restrict__ qw, const float* __restrict__ g1, const float* __restrict__ b1,
    const float* __restrict__ fw1, const float* __restrict__ g2, const float* __restrict__ b2,
    const float* __restrict__ X,
    ushort* __restrict__ WB, ushort* __restrict__ FW, float* __restrict__ CV,
    ushort* __restrict__ XT, float* __restrict__ STAT)
{
    __shared__ ushort tb[64][68];
    const int bid = blockIdx.x, t = threadIdx.x;
    if (bid < 288) {
        if (bid == 0 && t < 32) STAT[t] = 0.f;
        const int idx = (bid * 256 + t) * 4;  // < 294912
        const float* src;
        int off;
        if      (idx < 65536)  { src = cv1w; off = 0; }
        else if (idx < 98304)  { src = projw; off = 65536; }
        else if (idx < 163840) { src = f2w;  off = 98304; }
        else                   { src = cv2w; off = 163840; }
        float4 v = *(const float4*)&src[idx - off];
        ushort4 u;
        u.x = b16(v.x); u.y = b16(v.y); u.z = b16(v.z); u.w = b16(v.w);
        *(ushort4*)&WB[idx] = u;
    } else if (bid < 608) {
        // GN-fold: one wave per weight row, coalesced loads + shuffle reduce
        const int r = (bid - 288) * 4 + (t >> 6);   // 0..1279
        const int lane = t & 63;
        const int i = r / 640, rr = r % 640;
        const float* wrow; const float* ga; const float* bb; ushort* dst;
        int cvs, cvb;
        if (rr < 384) {
            wrow = qw + ((size_t)i * 384 + rr) * 128;
            ga = g1 + i * 128; bb = b1 + i * 128;
            dst = FW + (size_t)i * 49152 + rr * 128;
            cvs = i * 1280 + rr; cvb = i * 1280 + 384 + rr;
        } else {
            const int o = rr - 384;
            wrow = fw1 + ((size_t)i * 256 + o) * 128;
            ga = g2 + i * 128; bb = b2 + i * 128;
            dst = FW + 98304 + (size_t)i * 32768 + o * 128;
            cvs = i * 1280 + 768 + o; cvb = i * 1280 + 1024 + o;
        }
        const float w0 = wrow[lane], w1 = wrow[lane + 64];
        const float p0 = w0 * ga[lane], p1 = w1 * ga[lane + 64];
        dst[lane] = b16(p0); dst[lane + 64] = b16(p1);
        float sw = p0 + p1;
        float wb = w0 * bb[lane] + w1 * bb[lane + 64];
        #pragma unroll
        for (int off = 32; off; off >>= 1) { sw += __shfl_xor(sw, off); wb += __shfl_xor(wb, off); }
        if (lane == 0) { CV[cvs] = sw; CV[cvb] = wb; }
    } else {
        const int flat = bid - 608;                 // < 432
        const int bx = flat % 36, by = (flat / 36) % 4, bz = flat / 144;
        const int cb = by * 64, nb = bx * 64;
        #pragma unroll
        for (int k = 0; k < 4; k++) {
            const int row = k * 16 + (t >> 4), cq = t & 15;
            float4 v = *(const float4*)&X[(size_t)(bz * 256 + cb + row) * HW + nb + cq * 4];
            ushort4 u; u.x = b16(v.x); u.y = b16(v.y); u.z = b16(v.z); u.w = b16(v.w);
            *(ushort4*)&tb[row][cq * 4] = u;
        }
        __syncthreads();
        #pragma unroll
        for (int k = 0; k < 4; k++) {
            const int n = k * 16 + (t >> 4), cq = t & 15;
            ushort4 u;
            u.x = tb[cq * 4 + 0][n]; u.y = tb[cq * 4 + 1][n];
            u.z = tb[cq * 4 + 2][n]; u.w = tb[cq * 4 + 3][n];
            *(ushort4*)&XT[((size_t)bz * HW + nb + n) * 256 + cb + cq * 4] = u;
        }
    }
}

// ---- MFMA GEMM (cv1 / qkv): D[o][n] = sum_c W[o][c] * X[n][xoff+c] ----
// ONE WAVE per block (64 threads), 64o x 64n tile; grid (36, O/64, 3).
template <int EPI>
__global__ __launch_bounds__(64) void gemm_mfma(
    const ushort* __restrict__ W, const ushort* __restrict__ X,
    int K, int xld, int xoff,
    const float* __restrict__ q0, const float* __restrict__ q1,
    const float* __restrict__ q2, const float* __restrict__ q3,
    float* __restrict__ STAT, int slotUse, int slotAcc,
    const float* __restrict__ cvec,
    ushort* __restrict__ CT, int ycol,
    ushort* __restrict__ U0, ushort* __restrict__ U1, ushort* __restrict__ U2)
{
    const int b = blockIdx.z;
    const int l = threadIdx.x;
    const int ln = l & 15, lg = l >> 4;
    const int ob = blockIdx.y * 64;
    const int nb = blockIdx.x * 64;

    const ushort* ap = W + (size_t)(ob + ln) * K + lg * 8;
    const ushort* bp = X + ((size_t)b * HW + nb + ln) * xld + xoff + lg * 8;

    bf16x8 a0[4], bb0[4], a1[4], bb1[4];
    #pragma unroll
    for (int i = 0; i < 4; i++) {
        a0[i]  = *(const bf16x8*)(ap + (size_t)i * 16 * K);
        bb0[i] = *(const bf16x8*)(bp + (size_t)i * 16 * xld);
    }
    f32x4 acc[4][4];
    #pragma unroll
    for (int i = 0; i < 4; i++)
        #pragma unroll
        for (int j = 0; j < 4; j++) acc[i][j] = (f32x4){0.f, 0.f, 0.f, 0.f};

    for (int c0 = 32; c0 <= K; c0 += 32) {
        if (c0 < K) {
            #pragma unroll
            for (int i = 0; i < 4; i++) {
                a1[i]  = *(const bf16x8*)(ap + (size_t)i * 16 * K + c0);
                bb1[i] = *(const bf16x8*)(bp + (size_t)i * 16 * xld + c0);
            }
        }
        #pragma unroll
        for (int i = 0; i < 4; i++)
            #pragma unroll
            for (int j = 0; j < 4; j++)
                acc[i][j] = __builtin_amdgcn_mfma_f32_16x16x32_bf16(a0[i], bb0[j], acc[i][j], 0, 0, 0);
        #pragma unroll
        for (int i = 0; i < 4; i++) { a0[i] = a1[i]; bb0[i] = bb1[i]; }
    }

    float mu = 0.f, rs = 0.f;
    if (EPI == E_QKV) {
        const float s  = STAT[(slotUse * 3 + b) * 2];
        const float sq = STAT[(slotUse * 3 + b) * 2 + 1];
        mu = s * INV_N;
        rs = rsqrtf(sq * INV_N - mu * mu + EPSV);
    }
    float ls = 0.f, lsq = 0.f;

    #pragma unroll
    for (int i = 0; i < 4; i++) {
        const int obase = ob + i * 16 + lg * 4;
        if (EPI == E_CV1) {
            float sc[4], sh[4];
            #pragma unroll
            for (int r = 0; r < 4; r++) {
                const int o = obase + r;
                const float irs = rsqrtf(q3[o] + EPSV);
                sc[r] = q0[o] * irs;
                sh[r] = q1[o] - q2[o] * sc[r];
            }
            #pragma unroll
            for (int j = 0; j < 4; j++) {
                const int n = nb + j * 16 + ln;
                ushort4 u;
                #pragma unroll
                for (int r = 0; r < 4; r++) {
                    float y = fmaf(acc[i][j][r], sc[r], sh[r]);
                    y = y / (1.f + __expf(-y));
                    ls += y; lsq += y * y;
                    if (r == 0) u.x = b16(y); else if (r == 1) u.y = b16(y);
                    else if (r == 2) u.z = b16(y); else u.w = b16(y);
                }
                *(ushort4*)&CT[((size_t)b * HW + n) * 512 + ycol + obase] = u;
            }
        } else {  // E_QKV: Q=batch0's 384ch, K=batch1's, V=batch2's (reference quirk)
            const int gh = obase >> 5;
            const int d0 = obase & 31;
            float C[4];
            #pragma unroll
            for (int r = 0; r < 4; r++) {
                const int o = obase + r;
                C[r] = q0[o] + cvec[384 + o] - rs * mu * cvec[o];
            }
            #pragma unroll
            for (int j = 0; j < 4; j++) {
                const int n = nb + j * 16 + ln;
                float y0 = fmaf(rs, acc[i][j][0], C[0]);
                float y1 = fmaf(rs, acc[i][j][1], C[1]);
                float y2 = fmaf(rs, acc[i][j][2], C[2]);
                float y3 = fmaf(rs, acc[i][j][3], C[3]);
                if (b == 0) {
                    ushort4 u;
                    u.x = b16(y0 * QS_LOG2E); u.y = b16(y1 * QS_LOG2E);
                    u.z = b16(y2 * QS_LOG2E); u.w = b16(y3 * QS_LOG2E);
                    *(ushort4*)&U0[((size_t)gh * HW + n) * 32 + d0] = u;
                } else if (b == 1) {
                    ushort4 u;
                    u.x = b16(y0); u.y = b16(y1); u.z = b16(y2); u.w = b16(y3);
                    *(ushort4*)&U1[((size_t)gh * HW + n) * 32 + d0] = u;
                } else {
                    U2[(size_t)(obase + 0) * HW + n] = b16(y0);
                    U2[(size_t)(obase + 1) * HW + n] = b16(y1);
                    U2[(size_t)(obase + 2) * HW + n] = b16(y2);
                    U2[(size_t)(obase + 3) * HW + n] = b16(y3);
                }
            }
        }
    }
    if (EPI == E_CV1 && slotAcc >= 0 && blockIdx.y >= 2) stat_acc(STAT, slotAcc, b, ls, lsq);
}

// ---- fused FFN: F=gelu(f1(GN(Z))) in LDS -> y=f2(F)+res in-place (+stats);
// LAST: + cv2 over full 512 concat (cols 384+ from LDS) -> out fp32.
template <int LAST>
__global__ __launch_bounds__(256) void ffn_fused(
    const ushort* __restrict__ FW1, const float* __restrict__ f1b,
    const float* __restrict__ cvec,
    const ushort* __restrict__ W2, const float* __restrict__ f2b,
    ushort* __restrict__ CT, int col,
    float* __restrict__ STAT, int slotUse, int slotAcc,
    const ushort* __restrict__ WCV2, const float* __restrict__ q0,
    const float* __restrict__ q1, const float* __restrict__ q2,
    const float* __restrict__ q3, float* __restrict__ out)
{
    __shared__ __align__(16) ushort Fl[32][264];
    __shared__ __align__(16) ushort Yl[32][136];
    const int b = blockIdx.z, nb = blockIdx.x * 32;
    const int t = threadIdx.x, w = t >> 6, l = t & 63;
    const int ln = l & 15, lg = l >> 4;

    const float s  = STAT[(slotUse * 3 + b) * 2];
    const float sq = STAT[(slotUse * 3 + b) * 2 + 1];
    const float mu = s * INV_N;
    const float rs = rsqrtf(sq * INV_N - mu * mu + EPSV);

    // ---- stage A: F = gelu(rs*(FW1 . Z) + C), O=256, wave 64o x 32n
    {
        const int ob = w * 64;
        const ushort* ap = FW1 + (size_t)(ob + ln) * 128 + lg * 8;
        const ushort* bp = CT + ((size_t)b * HW + nb + ln) * 512 + col + lg * 8;
        f32x4 acc[4][2];
        #pragma unroll
        for (int i = 0; i < 4; i++)
            #pragma unroll
            for (int j = 0; j < 2; j++) acc[i][j] = (f32x4){0.f, 0.f, 0.f, 0.f};
        #pragma unroll
        for (int kk = 0; kk < 4; kk++) {
            bf16x8 bfr[2];
            #pragma unroll
            for (int j = 0; j < 2; j++)
                bfr[j] = *(const bf16x8*)(bp + (size_t)(j * 16) * 512 + kk * 32);
            #pragma unroll
            for (int i = 0; i < 4; i++) {
                const bf16x8 af = *(const bf16x8*)(ap + (size_t)(i * 16) * 128 + kk * 32);
                acc[i][0] = __builtin_amdgcn_mfma_f32_16x16x32_bf16(af, bfr[0], acc[i][0], 0, 0, 0);
                acc[i][1] = __builtin_amdgcn_mfma_f32_16x16x32_bf16(af, bfr[1], acc[i][1], 0, 0, 0);
            }
        }
        #pragma unroll
        for (int i = 0; i < 4; i++) {
            const int obase = ob + i * 16 + lg * 4;
            float C[4];
            #pragma unroll
            for (int r = 0; r < 4; r++) {
                const int o = obase + r;
                C[r] = f1b[o] + cvec[256 + o] - rs * mu * cvec[o];
            }
            #pragma unroll
            for (int j = 0; j < 2; j++) {
                const int n = j * 16 + ln;
                ushort4 u;
                #pragma unroll
                for (int r = 0; r < 4; r++) {
                    float y = fmaf(rs, acc[i][j][r], C[r]);
                    y = 0.5f * y * (1.f + erff(y * 0.70710678f));
                    if (r == 0) u.x = b16(y); else if (r == 1) u.y = b16(y);
                    else if (r == 2) u.z = b16(y); else u.w = b16(y);
                }
                *(ushort4*)&Fl[n][obase] = u;
            }
        }
    }
    __syncthreads();

    // ---- stage B: y = W2 . F + f2b + residual, O=128, wave 32o x 32n
    float ls = 0.f, lsq = 0.f;
    {
        const int wo = w * 32;
        const ushort* ap = W2 + (size_t)(wo + ln) * 256 + lg * 8;
        f32x4 acc[2][2];
        #pragma unroll
        for (int i = 0; i < 2; i++)
            #pragma unroll
            for (int j = 0; j < 2; j++) acc[i][j] = (f32x4){0.f, 0.f, 0.f, 0.f};
        #pragma unroll
        for (int kk = 0; kk < 8; kk++) {
            bf16x8 bfr[2];
            #pragma unroll
            for (int j = 0; j < 2; j++)
                bfr[j] = *(const bf16x8*)&Fl[j * 16 + ln][kk * 32 + lg * 8];
            #pragma unroll
            for (int i = 0; i < 2; i++) {
                const bf16x8 af = *(const bf16x8*)(ap + (size_t)(i * 16) * 256 + kk * 32);
                acc[i][0] = __builtin_amdgcn_mfma_f32_16x16x32_bf16(af, bfr[0], acc[i][0], 0, 0, 0);
                acc[i][1] = __builtin_amdgcn_mfma_f32_16x16x32_bf16(af, bfr[1], acc[i][1], 0, 0, 0);
            }
        }
        #pragma unroll
        for (int i = 0; i < 2; i++) {
            const int o4 = wo + i * 16 + lg * 4;
            #pragma unroll
            for (int j = 0; j < 2; j++) {
                const int n = nb + j * 16 + ln;
                ushort* cp = &CT[((size_t)b * HW + n) * 512 + col + o4];
                ushort4 rv = *(const ushort4*)cp;
                float y0 = acc[i][j][0] + f2b[o4 + 0] + bf(rv.x);
                float y1 = acc[i][j][1] + f2b[o4 + 1] + bf(rv.y);
                float y2 = acc[i][j][2] + f2b[o4 + 2] + bf(rv.z);
                float y3 = acc[i][j][3] + f2b[o4 + 3] + bf(rv.w);
                ls += (y0 + y1) + (y2 + y3);
                lsq += y0 * y0 + y1 * y1 + y2 * y2 + y3 * y3;
                ushort4 u;
                u.x = b16(y0); u.y = b16(y1); u.z = b16(y2); u.w = b16(y3);
                *(ushort4*)cp = u;
                if (LAST) *(ushort4*)&Yl[j * 16 + ln][o4] = u;
            }
        }
    }
    if (slotAcc >= 0) stat_acc(STAT, slotAcc, b, ls, lsq);

    if (LAST) {
        __syncthreads();
        // ---- stage C: cv2 BN+SiLU, O=256, K=512 (cols 0..383 global, 384+ LDS)
        const int ob = w * 64;
        const ushort* ap = WCV2 + (size_t)(ob + ln) * 512 + lg * 8;
        const ushort* bp = CT + ((size_t)b * HW + nb + ln) * 512 + lg * 8;
        f32x4 acc[4][2];
        #pragma unroll
        for (int i = 0; i < 4; i++)
            #pragma unroll
            for (int j = 0; j < 2; j++) acc[i][j] = (f32x4){0.f, 0.f, 0.f, 0.f};
        bf16x8 a0[4], b0[2], a1[4], b1[2];
        #pragma unroll
        for (int i = 0; i < 4; i++) a0[i] = *(const bf16x8*)(ap + (size_t)(i * 16) * 512);
        #pragma unroll
        for (int j = 0; j < 2; j++) b0[j] = *(const bf16x8*)(bp + (size_t)(j * 16) * 512);
        for (int c0 = 32; c0 <= 384; c0 += 32) {
            if (c0 < 384) {
                #pragma unroll
                for (int i = 0; i < 4; i++)
                    a1[i] = *(const bf16x8*)(ap + (size_t)(i * 16) * 512 + c0);
                #pragma unroll
                for (int j = 0; j < 2; j++)
                    b1[j] = *(const bf16x8*)(bp + (size_t)(j * 16) * 512 + c0);
            }
            #pragma unroll
            for (int i = 0; i < 4; i++) {
                acc[i][0] = __builtin_amdgcn_mfma_f32_16x16x32_bf16(a0[i], b0[0], acc[i][0], 0, 0, 0);
                acc[i][1] = __builtin_amdgcn_mfma_f32_16x16x32_bf16(a0[i], b0[1], acc[i][1], 0, 0, 0);
            }
            #pragma unroll
            for (int i = 0; i < 4; i++) a0[i] = a1[i];
            #pragma unroll
            for (int j = 0; j < 2; j++) b0[j] = b1[j];
        }
        #pragma unroll
        for (int kk = 0; kk < 4; kk++) {
            bf16x8 bfr[2];
            #pragma unroll
            for (int j = 0; j < 2; j++)
                bfr[j] = *(const bf16x8*)&Yl[j * 16 + ln][kk * 32 + lg * 8];
            #pragma unroll
            for (int i = 0; i < 4; i++) {
                const bf16x8 af = *(const bf16x8*)(ap + (size_t)(i * 16) * 512 + 384 + kk * 32);
                acc[i][0] = __builtin_amdgcn_mfma_f32_16x16x32_bf16(af, bfr[0], acc[i][0], 0, 0, 0);
                acc[i][1] = __builtin_amdgcn_mfma_f32_16x16x32_bf16(af, bfr[1], acc[i][1], 0, 0, 0);
            }
        }
        #pragma unroll
        for (int i = 0; i < 4; i++) {
            const int obase = ob + i * 16 + lg * 4;
            float sc[4], sh[4];
            #pragma unroll
            for (int r = 0; r < 4; r++) {
                const int o = obase + r;
                const float irs = rsqrtf(q3[o] + EPSV);
                sc[r] = q0[o] * irs;
                sh[r] = q1[o] - q2[o] * sc[r];
            }
            #pragma unroll
            for (int j = 0; j < 2; j++) {
                const int n = nb + j * 16 + ln;
                #pragma unroll
                for (int r = 0; r < 4; r++) {
                    float y = fmaf(acc[i][j][r], sc[r], sh[r]);
                    y = y / (1.f + __expf(-y));
                    out[(size_t)(b * 256 + obase + r) * HW + n] = y;
                }
            }
        }
    }
}

// ---- MFMA flash attention, split-K=4, LDS K/V, fixed softmax reference ----
// grid (36, 12, 4); 256 threads = 4 waves, each 16 queries; 64-key tiles.
__global__ __launch_bounds__(256) void attn_mfma(
    const ushort* __restrict__ QT,  // [12][HW][32] bf16, pre-scaled by QS_LOG2E
    const ushort* __restrict__ KT,  // [12][HW][32] bf16
    const ushort* __restrict__ VB,  // [384][HW] bf16
    ushort* __restrict__ PO,        // 4 slots bf16 (d_out)
    float* __restrict__ MS)         // [4][12][HW][2] (only [..][0] = S used)
{
    __shared__ __align__(16) ushort Kl[2][2048];
    __shared__ __align__(16) ushort Vl[2][2048];
    __shared__ __align__(16) ushort plds[4][16][72];
    const int gh = blockIdx.y, g = gh >> 2, h = gh & 3;
    const int sp = blockIdx.z;
    const int t = threadIdx.x, w = t >> 6, l = t & 63;
    const int ln = l & 15, lg = l >> 4;
    const int n0 = (blockIdx.x * 4 + w) * 16;
    const int ms0 = sp * 576, mend = ms0 + 576;

    const ushort* ktg = KT + (size_t)gh * HW * 32;
    const ushort* vg  = VB + ((size_t)g * 128 + h * 32) * HW;

    const int krow = t >> 2, kcq = t & 3;
    const int vrow = t >> 3, vcq = t & 7;
    const int kw = krow * 32 + ((kcq ^ (krow & 3)) << 3);
    const int vw = vrow * 64 + ((vcq ^ (vrow & 7)) << 3);
    const int krd = ln * 32 + ((lg ^ (ln & 3)) << 3);
    const int vs  = ln & 7;
    const int vrd0 = ln * 64 + ((lg ^ vs) << 3);
    const int vrd1 = ln * 64 + (((lg + 4) ^ vs) << 3);
    const int vrd2 = (16 + ln) * 64 + ((lg ^ vs) << 3);
    const int vrd3 = (16 + ln) * 64 + (((lg + 4) ^ vs) << 3);

    const bf16x8 qf = *(const bf16x8*)(QT + ((size_t)gh * HW + n0 + ln) * 32 + lg * 8);

    f32x4 o0 = {0.f, 0.f, 0.f, 0.f}, o1 = {0.f, 0.f, 0.f, 0.f};
    float S = 0.f;

    {
        bf16x8 kr = *(const bf16x8*)(ktg + (size_t)(ms0 + krow) * 32 + kcq * 8);
        bf16x8 vr = *(const bf16x8*)(vg + (size_t)vrow * HW + ms0 + vcq * 8);
        *(bf16x8*)&Kl[0][kw] = kr;
        *(bf16x8*)&Vl[0][vw] = vr;
    }
    int cur = 0;

    for (int m0 = ms0; m0 < mend; m0 += 64) {
        __syncthreads();
        const bool more = (m0 + 64 < mend);
        bf16x8 kr, vr;
        if (more) {
            kr = *(const bf16x8*)(ktg + (size_t)(m0 + 64 + krow) * 32 + kcq * 8);
            vr = *(const bf16x8*)(vg + (size_t)vrow * HW + m0 + 64 + vcq * 8);
        }

        f32x4 st[4];
        const f32x4 zero = {0.f, 0.f, 0.f, 0.f};
        __builtin_amdgcn_s_setprio(1);
        #pragma unroll
        for (int mc = 0; mc < 4; mc++) {
            const bf16x8 kf = *(const bf16x8*)&Kl[cur][mc * 512 + krd];
            st[mc] = __builtin_amdgcn_mfma_f32_16x16x32_bf16(kf, qf, zero, 0, 0, 0);
        }
        __builtin_amdgcn_s_setprio(0);

        // V fragments issued early: independent of softmax chain below
        const bf16x8 vf0 = *(const bf16x8*)&Vl[cur][vrd0];
        const bf16x8 vf1 = *(const bf16x8*)&Vl[cur][vrd1];
        const bf16x8 vf2 = *(const bf16x8*)&Vl[cur][vrd2];
        const bf16x8 vf3 = *(const bf16x8*)&Vl[cur][vrd3];

        // fixed-reference softmax: P = exp2(s - MFIX); no max tracking.
        float ps = 0.f;
        ushort4 pw[4];
        #pragma unroll
        for (int mc = 0; mc < 4; mc++) {
            float p0v = exp2f(st[mc][0] - MFIX), p1v = exp2f(st[mc][1] - MFIX);
            float p2v = exp2f(st[mc][2] - MFIX), p3v = exp2f(st[mc][3] - MFIX);
            ps += (p0v + p1v) + (p2v + p3v);
            pw[mc].x = b16(p0v); pw[mc].y = b16(p1v);
            pw[mc].z = b16(p2v); pw[mc].w = b16(p3v);
        }
        ps += __shfl_xor(ps, 16);
        ps += __shfl_xor(ps, 32);
        S += ps;

        #pragma unroll
        for (int mc = 0; mc < 4; mc++)
            *(ushort4*)&plds[w][ln][mc * 16 + lg * 4] = pw[mc];
        bf16x8 pf0 = *(const bf16x8*)&plds[w][ln][lg * 8];
        bf16x8 pf1 = *(const bf16x8*)&plds[w][ln][32 + lg * 8];

        __builtin_amdgcn_s_setprio(1);
        o0 = __builtin_amdgcn_mfma_f32_16x16x32_bf16(vf0, pf0, o0, 0, 0, 0);
        o0 = __builtin_amdgcn_mfma_f32_16x16x32_bf16(vf1, pf1, o0, 0, 0, 0);
        o1 = __builtin_amdgcn_mfma_f32_16x16x32_bf16(vf2, pf0, o1, 0, 0, 0);
        o1 = __builtin_amdgcn_mfma_f32_16x16x32_bf16(vf3, pf1, o1, 0, 0, 0);
        __builtin_amdgcn_s_setprio(0);

        if (more) {
            *(bf16x8*)&Kl[cur ^ 1][kw] = kr;
            *(bf16x8*)&Vl[cur ^ 1][vw] = vr;
        }
        cur ^= 1;
    }

    ushort* po = PO + (size_t)sp * 884736;
    #pragma unroll
    for (int r = 0; r < 4; r++) {
        const int d = lg * 4 + r;
        po[((size_t)gh * 32 + d) * HW + n0 + ln]      = b16(o0[r]);
        po[((size_t)gh * 32 + d + 16) * HW + n0 + ln] = b16(o1[r]);
    }
    if (lg == 0) {
        MS[(((size_t)sp * 12 + gh) * HW + n0 + ln) * 2] = S;
    }
}

// ---- merge 4 bf16 split-K partials + proj GEMM + residual -> CATT[ycol] ----
// fixed softmax reference: weight = 1 / sum_k S_k; grid (72, 3), 32 n/block.
__global__ __launch_bounds__(256) void merge_proj(
    const ushort* __restrict__ PO, const float* __restrict__ MS,
    const ushort* __restrict__ PW, const float* __restrict__ pb,
    ushort* __restrict__ CT, int rcol, int ycol,
    float* __restrict__ STAT, int slotAcc)
{
    __shared__ float fwv[4][32];   // [h][nl] = 1/sum S
    __shared__ __align__(16) unsigned long long obuf[32][34];  // [n][c/4]
    const int g = blockIdx.y, nb = blockIdx.x * 32;
    const int t = threadIdx.x;
    if (t < 128) {
        const int h = t >> 5, nl = t & 31, gh = g * 4 + h, n = nb + nl;
        float den = 0.f;
        #pragma unroll
        for (int k = 0; k < NSPLIT; k++)
            den += MS[(((size_t)k * 12 + gh) * HW + n) * 2];
        fwv[h][nl] = 1.f / den;
    }
    __syncthreads();
    {
        const int nl = t & 31, dd = t >> 5;     // dd 0..7
        #pragma unroll
        for (int p = 0; p < 4; p++) {
            const int d = p * 8 + dd;           // 0..31
            ushort uu[4];
            #pragma unroll
            for (int h = 0; h < 4; h++) {
                const int gh = g * 4 + h;
                const size_t idx = ((size_t)gh * 32 + d) * HW + nb + nl;
                float v = 0.f;
                #pragma unroll
                for (int k = 0; k < NSPLIT; k++)
                    v += bf(PO[(size_t)k * 884736 + idx]);
                uu[h] = b16(v * fwv[h][nl]);
            }
            obuf[nl][d] = (unsigned long long)uu[0] | ((unsigned long long)uu[1] << 16)
                        | ((unsigned long long)uu[2] << 32) | ((unsigned long long)uu[3] << 48);
        }
    }
    __syncthreads();
    // proj: y[o][n] = sum_c PW[o][c]*obuf[n][c], o<128, n<32 (c = d*4+h)
    const int w = t >> 6, l = t & 63, ln = l & 15, lg = l >> 4;
    const int wo = w * 32;
    const ushort* ob_base = (const ushort*)&obuf[0][0];  // row stride 136 ushorts
    const ushort* ap = PW + (size_t)(wo + ln) * 128 + lg * 8;
    f32x4 acc[2][2];
    #pragma unroll
    for (int i = 0; i < 2; i++)
        #pragma unroll
        for (int jf = 0; jf < 2; jf++) acc[i][jf] = (f32x4){0.f, 0.f, 0.f, 0.f};
    #pragma unroll
    for (int kk = 0; kk < 4; kk++) {
        bf16x8 bfr[2];
        #pragma unroll
        for (int jf = 0; jf < 2; jf++)
            bfr[jf] = *(const bf16x8*)(ob_base + (jf * 16 + ln) * 136 + kk * 32 + lg * 8);
        #pragma unroll
        for (int i = 0; i < 2; i++) {
            const bf16x8 af = *(const bf16x8*)(ap + (size_t)i * 16 * 128 + kk * 32);
            acc[i][0] = __builtin_amdgcn_mfma_f32_16x16x32_bf16(af, bfr[0], acc[i][0], 0, 0, 0);
            acc[i][1] = __builtin_amdgcn_mfma_f32_16x16x32_bf16(af, bfr[1], acc[i][1], 0, 0, 0);
        }
    }
    float ls = 0.f, lsq = 0.f;
    #pragma unroll
    for (int i = 0; i < 2; i++) {
        const int o4 = wo + i * 16 + lg * 4;
        #pragma unroll
        for (int jf = 0; jf < 2; jf++) {
            const int n = nb + jf * 16 + ln;
            const size_t base = ((size_t)g * HW + n) * 512;
            ushort4 rv = *(const ushort4*)&CT[base + rcol + o4];
            float y0 = acc[i][jf][0] + pb[o4 + 0] + bf(rv.x);
            float y1 = acc[i][jf][1] + pb[o4 + 1] + bf(rv.y);
            float y2 = acc[i][jf][2] + pb[o4 + 2] + bf(rv.z);
            float y3 = acc[i][jf][3] + pb[o4 + 3] + bf(rv.w);
            ls += (y0 + y1) + (y2 + y3);
            lsq += y0 * y0 + y1 * y1 + y2 * y2 + y3 * y3;
            ushort4 u;
            u.x = b16(y0); u.y = b16(y1); u.z = b16(y2); u.w = b16(y3);
            *(ushort4*)&CT[base + ycol + o4] = u;
        }
    }
    stat_acc(STAT, slotAcc, g, ls, lsq);
}

extern "C" void kernel_launch(void* const* d_in, const int* in_sizes, int n_in,
                              void* d_out, int out_size, void* d_ws, size_t ws_size,
                              hipStream_t stream)
{
    (void)in_sizes; (void)n_in; (void)out_size; (void)ws_size;
    const float* x      = (const float*)d_in[0];
    const float* cv1_w  = (const float*)d_in[1];
    const float* cv1_g  = (const float*)d_in[2];
    const float* cv1_b  = (const float*)d_in[3];
    const float* cv1_m  = (const float*)d_in[4];
    const float* cv1_v  = (const float*)d_in[5];
    const float* n1_g   = (const float*)d_in[6];
    const float* n1_b   = (const float*)d_in[7];
    const float* qkv_w  = (const float*)d_in[8];
    const float* qkv_b  = (const float*)d_in[9];
    const float* proj_w = (const float*)d_in[10];
    const float* proj_b = (const float*)d_in[11];
    const float* n2_g   = (const float*)d_in[12];
    const float* n2_b   = (const float*)d_in[13];
    const float* f1_w   = (const float*)d_in[14];
    const float* f1_b   = (const float*)d_in[15];
    const float* f2_w   = (const float*)d_in[16];
    const float* f2_b   = (const float*)d_in[17];
    const float* cv2_w  = (const float*)d_in[18];
    const float* cv2_g  = (const float*)d_in[19];
    const float* cv2_b  = (const float*)d_in[20];
    const float* cv2_m  = (const float*)d_in[21];
    const float* cv2_v  = (const float*)d_in[22];
    float* out = (float*)d_out;

    float* ws = (float*)d_ws;
    ushort* CATT = (ushort*)ws;                      // [3][HW][512] bf16
    ushort* QT   = (ushort*)(ws + 1769472);          // [12][HW][32]
    ushort* KTb  = (ushort*)(ws + 2211840);          // [12][HW][32]
    ushort* VB   = (ushort*)(ws + 2654208);          // [384][HW]
    float*  MS   = ws + 3096576;                     // [4][12][HW][2]
    ushort* WB   = (ushort*)(ws + 3428352);          // 294912 bf16: cv1|proj|f2|cv2
    ushort* FW   = (ushort*)(ws + 3575808);          // 163840 bf16 folded qkv|f1
    float*  CV   = ws + 3657728;                     // 2560 f corrections
    float*  STAT = ws + 3660288;                     // 64 f
    ushort* XTX  = (ushort*)(ws + 3660352);          // [3][HW][256] bf16 (dead after cv1)
    ushort* PO   = (ushort*)d_out;                   // 4 x 884736 bf16 (= d_out exactly)

    dim3 blk(256);

    prep<<<dim3(1040), blk, 0, stream>>>(
        cv1_w, proj_w, f2_w, cv2_w, qkv_w, n1_g, n1_b, f1_w, n2_g, n2_b,
        x, WB, FW, CV, XTX, STAT);

    // cv1: BN+SiLU -> CATT cols 0..255; stats(slot0) over cols 128..255
    gemm_mfma<E_CV1><<<dim3(36, 4, 3), dim3(64), 0, stream>>>(
        WB + 0, XTX, 256, 256, 0, cv1_g, cv1_b, cv1_m, cv1_v,
        STAT, -1, 0, nullptr, CATT, 0, nullptr, nullptr, nullptr);

    for (int i = 0; i < 2; i++) {
        const int prev = (i == 0) ? 128 : 256;
        const int next = 256 + 128 * i;
        const int gn1 = (i == 0) ? 0 : 2;   // stats slot consumed by qkv
        const int gn2 = (i == 0) ? 1 : 3;   // stats slot consumed by ffn

        gemm_mfma<E_QKV><<<dim3(36, 6, 3), dim3(64), 0, stream>>>(
            FW + (size_t)i * 49152, CATT, 128, 512, prev, qkv_b + i * 384,
            nullptr, nullptr, nullptr, STAT, gn1, -1, CV + i * 1280,
            nullptr, 0, QT, KTb, VB);
        attn_mfma<<<dim3(36, 12, NSPLIT), blk, 0, stream>>>(QT, KTb, VB, PO, MS);
        merge_proj<<<dim3(72, 3), blk, 0, stream>>>(
            PO, MS, WB + 65536 + (size_t)i * 16384, proj_b + i * 128,
            CATT, prev, next, STAT, gn2);

        if (i == 0) {
            ffn_fused<0><<<dim3(72, 1, 3), blk, 0, stream>>>(
                FW + 98304, f1_b, CV + 768,
                WB + 98304, f2_b, CATT, 256, STAT, 1, 2,
                nullptr, nullptr, nullptr, nullptr, nullptr, nullptr);
        } else {
            ffn_fused<1><<<dim3(72, 1, 3), blk, 0, stream>>>(
                FW + 98304 + 32768, f1_b + 256, CV + 1280 + 768,
                WB + 98304 + 32768, f2_b + 128, CATT, 384, STAT, 3, -1,
                WB + 163840, cv2_g, cv2_b, cv2_m, cv2_v, out);
        }
    }
}

// Round 19
// 185.969 us; speedup vs baseline: 1.1020x; 1.1020x over previous
//
#include <hip/hip_runtime.h>
#include <hip/hip_bf16.h>
#include <math.h>

#define HW 2304
#define EPSV 1e-5f
#define INV_N (1.f / 294912.f)
// ATT_SCALE * log2(e): softmax runs in exp2 domain
#define QS_LOG2E (0.17677669529663687f * 1.44269504088896340f)
#define NSPLIT 4
// fixed exp2-domain softmax reference: scores are GN-normalized (sigma~1.5,
// max ~10); safe headroom to ~110. Cancels exactly in normalization.
#define MFIX 12.0f

enum { E_CV1 = 0, E_QKV = 1 };

typedef __attribute__((ext_vector_type(8))) short bf16x8;
typedef __attribute__((ext_vector_type(4))) float f32x4;

static __device__ __forceinline__ ushort b16(float f) {
    union { __hip_bfloat16 h; ushort u; } cv;
    cv.h = __float2bfloat16(f);
    return cv.u;
}
static __device__ __forceinline__ float bf(ushort u) {
    union { unsigned u; float f; } c; c.u = (unsigned)u << 16; return c.f;
}
// wave-reduce then 2 atomicAdds into STAT slot
static __device__ __forceinline__ void stat_acc(float* STAT, int slot, int b,
                                                float s, float sq) {
    #pragma unroll
    for (int off = 32; off; off >>= 1) { s += __shfl_xor(s, off); sq += __shfl_xor(sq, off); }
    if ((threadIdx.x & 63) == 0) {
        atomicAdd(&STAT[(slot * 3 + b) * 2], s);
        atomicAdd(&STAT[(slot * 3 + b) * 2 + 1], sq);
    }
}

// ---- prep: weight cvt + GN-fold (wave-parallel) + x transpose + STAT zero ----
__global__ __launch_bounds__(256) void prep(
    const float* __restrict__ cv1w, const float* __restrict__ projw,
    const float* __restrict__ f2w, const float* __restrict__ cv2w,
    const float* __restrict__ qw, const float* __restrict__ g1, const float* __restrict__ b1,
    const float* __restrict__ fw1, const float* __restrict__ g2, const float* __restrict__ b2,
    const float* __restrict__ X,
    ushort* __restrict__ WB, ushort* __restrict__ FW, float* __restrict__ CV,
    ushort* __restrict__ XT, float* __restrict__ STAT)
{
    __shared__ ushort tb[64][68];
    const int bid = blockIdx.x, t = threadIdx.x;
    if (bid < 288) {
        if (bid == 0 && t < 32) STAT[t] = 0.f;
        const int idx = (bid * 256 + t) * 4;  // < 294912
        const float* src;
        int off;
        if      (idx < 65536)  { src = cv1w; off = 0; }
        else if (idx < 98304)  { src = projw; off = 65536; }
        else if (idx < 163840) { src = f2w;  off = 98304; }
        else                   { src = cv2w; off = 163840; }
        float4 v = *(const float4*)&src[idx - off];
        ushort4 u;
        u.x = b16(v.x); u.y = b16(v.y); u.z = b16(v.z); u.w = b16(v.w);
        *(ushort4*)&WB[idx] = u;
    } else if (bid < 608) {
        // GN-fold: one wave per weight row, coalesced loads + shuffle reduce
        const int r = (bid - 288) * 4 + (t >> 6);   // 0..1279
        const int lane = t & 63;
        const int i = r / 640, rr = r % 640;
        const float* wrow; const float* ga; const float* bb; ushort* dst;
        int cvs, cvb;
        if (rr < 384) {
            wrow = qw + ((size_t)i * 384 + rr) * 128;
            ga = g1 + i * 128; bb = b1 + i * 128;
            dst = FW + (size_t)i * 49152 + rr * 128;
            cvs = i * 1280 + rr; cvb = i * 1280 + 384 + rr;
        } else {
            const int o = rr - 384;
            wrow = fw1 + ((size_t)i * 256 + o) * 128;
            ga = g2 + i * 128; bb = b2 + i * 128;
            dst = FW + 98304 + (size_t)i * 32768 + o * 128;
            cvs = i * 1280 + 768 + o; cvb = i * 1280 + 1024 + o;
        }
        const float w0 = wrow[lane], w1 = wrow[lane + 64];
        const float p0 = w0 * ga[lane], p1 = w1 * ga[lane + 64];
        dst[lane] = b16(p0); dst[lane + 64] = b16(p1);
        float sw = p0 + p1;
        float wb = w0 * bb[lane] + w1 * bb[lane + 64];
        #pragma unroll
        for (int off = 32; off; off >>= 1) { sw += __shfl_xor(sw, off); wb += __shfl_xor(wb, off); }
        if (lane == 0) { CV[cvs] = sw; CV[cvb] = wb; }
    } else {
        const int flat = bid - 608;                 // < 432
        const int bx = flat % 36, by = (flat / 36) % 4, bz = flat / 144;
        const int cb = by * 64, nb = bx * 64;
        #pragma unroll
        for (int k = 0; k < 4; k++) {
            const int row = k * 16 + (t >> 4), cq = t & 15;
            float4 v = *(const float4*)&X[(size_t)(bz * 256 + cb + row) * HW + nb + cq * 4];
            ushort4 u; u.x = b16(v.x); u.y = b16(v.y); u.z = b16(v.z); u.w = b16(v.w);
            *(ushort4*)&tb[row][cq * 4] = u;
        }
        __syncthreads();
        #pragma unroll
        for (int k = 0; k < 4; k++) {
            const int n = k * 16 + (t >> 4), cq = t & 15;
            ushort4 u;
            u.x = tb[cq * 4 + 0][n]; u.y = tb[cq * 4 + 1][n];
            u.z = tb[cq * 4 + 2][n]; u.w = tb[cq * 4 + 3][n];
            *(ushort4*)&XT[((size_t)bz * HW + nb + n) * 256 + cb + cq * 4] = u;
        }
    }
}

// ---- MFMA GEMM (cv1 / qkv): D[o][n] = sum_c W[o][c] * X[n][xoff+c] ----
// ONE WAVE per block (64 threads), 64o x 64n tile; grid (36, O/64, 3).
template <int EPI>
__global__ __launch_bounds__(64) void gemm_mfma(
    const ushort* __restrict__ W, const ushort* __restrict__ X,
    int K, int xld, int xoff,
    const float* __restrict__ q0, const float* __restrict__ q1,
    const float* __restrict__ q2, const float* __restrict__ q3,
    float* __restrict__ STAT, int slotUse, int slotAcc,
    const float* __restrict__ cvec,
    ushort* __restrict__ CT, int ycol,
    ushort* __restrict__ U0, ushort* __restrict__ U1, ushort* __restrict__ U2)
{
    const int b = blockIdx.z;
    const int l = threadIdx.x;
    const int ln = l & 15, lg = l >> 4;
    const int ob = blockIdx.y * 64;
    const int nb = blockIdx.x * 64;

    const ushort* ap = W + (size_t)(ob + ln) * K + lg * 8;
    const ushort* bp = X + ((size_t)b * HW + nb + ln) * xld + xoff + lg * 8;

    bf16x8 a0[4], bb0[4], a1[4], bb1[4];
    #pragma unroll
    for (int i = 0; i < 4; i++) {
        a0[i]  = *(const bf16x8*)(ap + (size_t)i * 16 * K);
        bb0[i] = *(const bf16x8*)(bp + (size_t)i * 16 * xld);
    }
    f32x4 acc[4][4];
    #pragma unroll
    for (int i = 0; i < 4; i++)
        #pragma unroll
        for (int j = 0; j < 4; j++) acc[i][j] = (f32x4){0.f, 0.f, 0.f, 0.f};

    for (int c0 = 32; c0 <= K; c0 += 32) {
        if (c0 < K) {
            #pragma unroll
            for (int i = 0; i < 4; i++) {
                a1[i]  = *(const bf16x8*)(ap + (size_t)i * 16 * K + c0);
                bb1[i] = *(const bf16x8*)(bp + (size_t)i * 16 * xld + c0);
            }
        }
        #pragma unroll
        for (int i = 0; i < 4; i++)
            #pragma unroll
            for (int j = 0; j < 4; j++)
                acc[i][j] = __builtin_amdgcn_mfma_f32_16x16x32_bf16(a0[i], bb0[j], acc[i][j], 0, 0, 0);
        #pragma unroll
        for (int i = 0; i < 4; i++) { a0[i] = a1[i]; bb0[i] = bb1[i]; }
    }

    float mu = 0.f, rs = 0.f;
    if (EPI == E_QKV) {
        const float s  = STAT[(slotUse * 3 + b) * 2];
        const float sq = STAT[(slotUse * 3 + b) * 2 + 1];
        mu = s * INV_N;
        rs = rsqrtf(sq * INV_N - mu * mu + EPSV);
    }
    float ls = 0.f, lsq = 0.f;

    #pragma unroll
    for (int i = 0; i < 4; i++) {
        const int obase = ob + i * 16 + lg * 4;
        if (EPI == E_CV1) {
            float sc[4], sh[4];
            #pragma unroll
            for (int r = 0; r < 4; r++) {
                const int o = obase + r;
                const float irs = rsqrtf(q3[o] + EPSV);
                sc[r] = q0[o] * irs;
                sh[r] = q1[o] - q2[o] * sc[r];
            }
            #pragma unroll
            for (int j = 0; j < 4; j++) {
                const int n = nb + j * 16 + ln;
                ushort4 u;
                #pragma unroll
                for (int r = 0; r < 4; r++) {
                    float y = fmaf(acc[i][j][r], sc[r], sh[r]);
                    y = y / (1.f + __expf(-y));
                    ls += y; lsq += y * y;
                    if (r == 0) u.x = b16(y); else if (r == 1) u.y = b16(y);
                    else if (r == 2) u.z = b16(y); else u.w = b16(y);
                }
                *(ushort4*)&CT[((size_t)b * HW + n) * 512 + ycol + obase] = u;
            }
        } else {  // E_QKV: Q=batch0's 384ch, K=batch1's, V=batch2's (reference quirk)
            const int gh = obase >> 5;
            const int d0 = obase & 31;
            float C[4];
            #pragma unroll
            for (int r = 0; r < 4; r++) {
                const int o = obase + r;
                C[r] = q0[o] + cvec[384 + o] - rs * mu * cvec[o];
            }
            #pragma unroll
            for (int j = 0; j < 4; j++) {
                const int n = nb + j * 16 + ln;
                float y0 = fmaf(rs, acc[i][j][0], C[0]);
                float y1 = fmaf(rs, acc[i][j][1], C[1]);
                float y2 = fmaf(rs, acc[i][j][2], C[2]);
                float y3 = fmaf(rs, acc[i][j][3], C[3]);
                if (b == 0) {
                    ushort4 u;
                    u.x = b16(y0 * QS_LOG2E); u.y = b16(y1 * QS_LOG2E);
                    u.z = b16(y2 * QS_LOG2E); u.w = b16(y3 * QS_LOG2E);
                    *(ushort4*)&U0[((size_t)gh * HW + n) * 32 + d0] = u;
                } else if (b == 1) {
                    ushort4 u;
                    u.x = b16(y0); u.y = b16(y1); u.z = b16(y2); u.w = b16(y3);
                    *(ushort4*)&U1[((size_t)gh * HW + n) * 32 + d0] = u;
                } else {
                    U2[(size_t)(obase + 0) * HW + n] = b16(y0);
                    U2[(size_t)(obase + 1) * HW + n] = b16(y1);
                    U2[(size_t)(obase + 2) * HW + n] = b16(y2);
                    U2[(size_t)(obase + 3) * HW + n] = b16(y3);
                }
            }
        }
    }
    if (EPI == E_CV1 && slotAcc >= 0 && blockIdx.y >= 2) stat_acc(STAT, slotAcc, b, ls, lsq);
}

// ---- fused FFN: F=gelu(f1(GN(Z))) in LDS -> y=f2(F)+res in-place (+stats);
// LAST: + cv2 over full 512 concat (cols 384+ from LDS) -> out fp32.
template <int LAST>
__global__ __launch_bounds__(256) void ffn_fused(
    const ushort* __restrict__ FW1, const float* __restrict__ f1b,
    const float* __restrict__ cvec,
    const ushort* __restrict__ W2, const float* __restrict__ f2b,
    ushort* __restrict__ CT, int col,
    float* __restrict__ STAT, int slotUse, int slotAcc,
    const ushort* __restrict__ WCV2, const float* __restrict__ q0,
    const float* __restrict__ q1, const float* __restrict__ q2,
    const float* __restrict__ q3, float* __restrict__ out)
{
    __shared__ __align__(16) ushort Fl[32][264];
    __shared__ __align__(16) ushort Yl[32][136];
    const int b = blockIdx.z, nb = blockIdx.x * 32;
    const int t = threadIdx.x, w = t >> 6, l = t & 63;
    const int ln = l & 15, lg = l >> 4;

    const float s  = STAT[(slotUse * 3 + b) * 2];
    const float sq = STAT[(slotUse * 3 + b) * 2 + 1];
    const float mu = s * INV_N;
    const float rs = rsqrtf(sq * INV_N - mu * mu + EPSV);

    // ---- stage A: F = gelu(rs*(FW1 . Z) + C), O=256, wave 64o x 32n
    {
        const int ob = w * 64;
        const ushort* ap = FW1 + (size_t)(ob + ln) * 128 + lg * 8;
        const ushort* bp = CT + ((size_t)b * HW + nb + ln) * 512 + col + lg * 8;
        f32x4 acc[4][2];
        #pragma unroll
        for (int i = 0; i < 4; i++)
            #pragma unroll
            for (int j = 0; j < 2; j++) acc[i][j] = (f32x4){0.f, 0.f, 0.f, 0.f};
        #pragma unroll
        for (int kk = 0; kk < 4; kk++) {
            bf16x8 bfr[2];
            #pragma unroll
            for (int j = 0; j < 2; j++)
                bfr[j] = *(const bf16x8*)(bp + (size_t)(j * 16) * 512 + kk * 32);
            #pragma unroll
            for (int i = 0; i < 4; i++) {
                const bf16x8 af = *(const bf16x8*)(ap + (size_t)(i * 16) * 128 + kk * 32);
                acc[i][0] = __builtin_amdgcn_mfma_f32_16x16x32_bf16(af, bfr[0], acc[i][0], 0, 0, 0);
                acc[i][1] = __builtin_amdgcn_mfma_f32_16x16x32_bf16(af, bfr[1], acc[i][1], 0, 0, 0);
            }
        }
        #pragma unroll
        for (int i = 0; i < 4; i++) {
            const int obase = ob + i * 16 + lg * 4;
            float C[4];
            #pragma unroll
            for (int r = 0; r < 4; r++) {
                const int o = obase + r;
                C[r] = f1b[o] + cvec[256 + o] - rs * mu * cvec[o];
            }
            #pragma unroll
            for (int j = 0; j < 2; j++) {
                const int n = j * 16 + ln;
                ushort4 u;
                #pragma unroll
                for (int r = 0; r < 4; r++) {
                    float y = fmaf(rs, acc[i][j][r], C[r]);
                    y = 0.5f * y * (1.f + erff(y * 0.70710678f));
                    if (r == 0) u.x = b16(y); else if (r == 1) u.y = b16(y);
                    else if (r == 2) u.z = b16(y); else u.w = b16(y);
                }
                *(ushort4*)&Fl[n][obase] = u;
            }
        }
    }
    __syncthreads();

    // ---- stage B: y = W2 . F + f2b + residual, O=128, wave 32o x 32n
    float ls = 0.f, lsq = 0.f;
    {
        const int wo = w * 32;
        const ushort* ap = W2 + (size_t)(wo + ln) * 256 + lg * 8;
        f32x4 acc[2][2];
        #pragma unroll
        for (int i = 0; i < 2; i++)
            #pragma unroll
            for (int j = 0; j < 2; j++) acc[i][j] = (f32x4){0.f, 0.f, 0.f, 0.f};
        #pragma unroll
        for (int kk = 0; kk < 8; kk++) {
            bf16x8 bfr[2];
            #pragma unroll
            for (int j = 0; j < 2; j++)
                bfr[j] = *(const bf16x8*)&Fl[j * 16 + ln][kk * 32 + lg * 8];
            #pragma unroll
            for (int i = 0; i < 2; i++) {
                const bf16x8 af = *(const bf16x8*)(ap + (size_t)(i * 16) * 256 + kk * 32);
                acc[i][0] = __builtin_amdgcn_mfma_f32_16x16x32_bf16(af, bfr[0], acc[i][0], 0, 0, 0);
                acc[i][1] = __builtin_amdgcn_mfma_f32_16x16x32_bf16(af, bfr[1], acc[i][1], 0, 0, 0);
            }
        }
        #pragma unroll
        for (int i = 0; i < 2; i++) {
            const int o4 = wo + i * 16 + lg * 4;
            #pragma unroll
            for (int j = 0; j < 2; j++) {
                const int n = nb + j * 16 + ln;
                ushort* cp = &CT[((size_t)b * HW + n) * 512 + col + o4];
                ushort4 rv = *(const ushort4*)cp;
                float y0 = acc[i][j][0] + f2b[o4 + 0] + bf(rv.x);
                float y1 = acc[i][j][1] + f2b[o4 + 1] + bf(rv.y);
                float y2 = acc[i][j][2] + f2b[o4 + 2] + bf(rv.z);
                float y3 = acc[i][j][3] + f2b[o4 + 3] + bf(rv.w);
                ls += (y0 + y1) + (y2 + y3);
                lsq += y0 * y0 + y1 * y1 + y2 * y2 + y3 * y3;
                ushort4 u;
                u.x = b16(y0); u.y = b16(y1); u.z = b16(y2); u.w = b16(y3);
                *(ushort4*)cp = u;
                if (LAST) *(ushort4*)&Yl[j * 16 + ln][o4] = u;
            }
        }
    }
    if (slotAcc >= 0) stat_acc(STAT, slotAcc, b, ls, lsq);

    if (LAST) {
        __syncthreads();
        // ---- stage C: cv2 BN+SiLU, O=256, K=512 (cols 0..383 global, 384+ LDS)
        const int ob = w * 64;
        const ushort* ap = WCV2 + (size_t)(ob + ln) * 512 + lg * 8;
        const ushort* bp = CT + ((size_t)b * HW + nb + ln) * 512 + lg * 8;
        f32x4 acc[4][2];
        #pragma unroll
        for (int i = 0; i < 4; i++)
            #pragma unroll
            for (int j = 0; j < 2; j++) acc[i][j] = (f32x4){0.f, 0.f, 0.f, 0.f};
        bf16x8 a0[4], b0[2], a1[4], b1[2];
        #pragma unroll
        for (int i = 0; i < 4; i++) a0[i] = *(const bf16x8*)(ap + (size_t)(i * 16) * 512);
        #pragma unroll
        for (int j = 0; j < 2; j++) b0[j] = *(const bf16x8*)(bp + (size_t)(j * 16) * 512);
        for (int c0 = 32; c0 <= 384; c0 += 32) {
            if (c0 < 384) {
                #pragma unroll
                for (int i = 0; i < 4; i++)
                    a1[i] = *(const bf16x8*)(ap + (size_t)(i * 16) * 512 + c0);
                #pragma unroll
                for (int j = 0; j < 2; j++)
                    b1[j] = *(const bf16x8*)(bp + (size_t)(j * 16) * 512 + c0);
            }
            #pragma unroll
            for (int i = 0; i < 4; i++) {
                acc[i][0] = __builtin_amdgcn_mfma_f32_16x16x32_bf16(a0[i], b0[0], acc[i][0], 0, 0, 0);
                acc[i][1] = __builtin_amdgcn_mfma_f32_16x16x32_bf16(a0[i], b0[1], acc[i][1], 0, 0, 0);
            }
            #pragma unroll
            for (int i = 0; i < 4; i++) a0[i] = a1[i];
            #pragma unroll
            for (int j = 0; j < 2; j++) b0[j] = b1[j];
        }
        #pragma unroll
        for (int kk = 0; kk < 4; kk++) {
            bf16x8 bfr[2];
            #pragma unroll
            for (int j = 0; j < 2; j++)
                bfr[j] = *(const bf16x8*)&Yl[j * 16 + ln][kk * 32 + lg * 8];
            #pragma unroll
            for (int i = 0; i < 4; i++) {
                const bf16x8 af = *(const bf16x8*)(ap + (size_t)(i * 16) * 512 + 384 + kk * 32);
                acc[i][0] = __builtin_amdgcn_mfma_f32_16x16x32_bf16(af, bfr[0], acc[i][0], 0, 0, 0);
                acc[i][1] = __builtin_amdgcn_mfma_f32_16x16x32_bf16(af, bfr[1], acc[i][1], 0, 0, 0);
            }
        }
        #pragma unroll
        for (int i = 0; i < 4; i++) {
            const int obase = ob + i * 16 + lg * 4;
            float sc[4], sh[4];
            #pragma unroll
            for (int r = 0; r < 4; r++) {
                const int o = obase + r;
                const float irs = rsqrtf(q3[o] + EPSV);
                sc[r] = q0[o] * irs;
                sh[r] = q1[o] - q2[o] * sc[r];
            }
            #pragma unroll
            for (int j = 0; j < 2; j++) {
                const int n = nb + j * 16 + ln;
                #pragma unroll
                for (int r = 0; r < 4; r++) {
                    float y = fmaf(acc[i][j][r], sc[r], sh[r]);
                    y = y / (1.f + __expf(-y));
                    out[(size_t)(b * 256 + obase + r) * HW + n] = y;
                }
            }
        }
    }
}

// ---- MFMA flash attention, split-K=4, LDS K/V, fixed softmax reference ----
// grid (36, 12, 4); 256 threads = 4 waves, each 16 queries; 64-key tiles.
__global__ __launch_bounds__(256) void attn_mfma(
    const ushort* __restrict__ QT,  // [12][HW][32] bf16, pre-scaled by QS_LOG2E
    const ushort* __restrict__ KT,  // [12][HW][32] bf16
    const ushort* __restrict__ VB,  // [384][HW] bf16
    ushort* __restrict__ PO,        // 4 slots bf16 (d_out)
    float* __restrict__ MS)         // [4][12][HW][2] (only [..][0] = S used)
{
    __shared__ __align__(16) ushort Kl[2][2048];
    __shared__ __align__(16) ushort Vl[2][2048];
    __shared__ __align__(16) ushort plds[4][16][72];
    const int gh = blockIdx.y, g = gh >> 2, h = gh & 3;
    const int sp = blockIdx.z;
    const int t = threadIdx.x, w = t >> 6, l = t & 63;
    const int ln = l & 15, lg = l >> 4;
    const int n0 = (blockIdx.x * 4 + w) * 16;
    const int ms0 = sp * 576, mend = ms0 + 576;

    const ushort* ktg = KT + (size_t)gh * HW * 32;
    const ushort* vg  = VB + ((size_t)g * 128 + h * 32) * HW;

    const int krow = t >> 2, kcq = t & 3;
    const int vrow = t >> 3, vcq = t & 7;
    const int kw = krow * 32 + ((kcq ^ (krow & 3)) << 3);
    const int vw = vrow * 64 + ((vcq ^ (vrow & 7)) << 3);
    const int krd = ln * 32 + ((lg ^ (ln & 3)) << 3);
    const int vs  = ln & 7;
    const int vrd0 = ln * 64 + ((lg ^ vs) << 3);
    const int vrd1 = ln * 64 + (((lg + 4) ^ vs) << 3);
    const int vrd2 = (16 + ln) * 64 + ((lg ^ vs) << 3);
    const int vrd3 = (16 + ln) * 64 + (((lg + 4) ^ vs) << 3);

    const bf16x8 qf = *(const bf16x8*)(QT + ((size_t)gh * HW + n0 + ln) * 32 + lg * 8);

    f32x4 o0 = {0.f, 0.f, 0.f, 0.f}, o1 = {0.f, 0.f, 0.f, 0.f};
    float S = 0.f;

    {
        bf16x8 kr = *(const bf16x8*)(ktg + (size_t)(ms0 + krow) * 32 + kcq * 8);
        bf16x8 vr = *(const bf16x8*)(vg + (size_t)vrow * HW + ms0 + vcq * 8);
        *(bf16x8*)&Kl[0][kw] = kr;
        *(bf16x8*)&Vl[0][vw] = vr;
    }
    int cur = 0;

    for (int m0 = ms0; m0 < mend; m0 += 64) {
        __syncthreads();
        const bool more = (m0 + 64 < mend);
        bf16x8 kr, vr;
        if (more) {
            kr = *(const bf16x8*)(ktg + (size_t)(m0 + 64 + krow) * 32 + kcq * 8);
            vr = *(const bf16x8*)(vg + (size_t)vrow * HW + m0 + 64 + vcq * 8);
        }

        f32x4 st[4];
        const f32x4 zero = {0.f, 0.f, 0.f, 0.f};
        __builtin_amdgcn_s_setprio(1);
        #pragma unroll
        for (int mc = 0; mc < 4; mc++) {
            const bf16x8 kf = *(const bf16x8*)&Kl[cur][mc * 512 + krd];
            st[mc] = __builtin_amdgcn_mfma_f32_16x16x32_bf16(kf, qf, zero, 0, 0, 0);
        }
        __builtin_amdgcn_s_setprio(0);

        // V fragments issued early: independent of softmax chain below
        const bf16x8 vf0 = *(const bf16x8*)&Vl[cur][vrd0];
        const bf16x8 vf1 = *(const bf16x8*)&Vl[cur][vrd1];
        const bf16x8 vf2 = *(const bf16x8*)&Vl[cur][vrd2];
        const bf16x8 vf3 = *(const bf16x8*)&Vl[cur][vrd3];

        // fixed-reference softmax: P = exp2(s - MFIX); no max tracking.
        float ps = 0.f;
        ushort4 pw[4];
        #pragma unroll
        for (int mc = 0; mc < 4; mc++) {
            float p0v = exp2f(st[mc][0] - MFIX), p1v = exp2f(st[mc][1] - MFIX);
            float p2v = exp2f(st[mc][2] - MFIX), p3v = exp2f(st[mc][3] - MFIX);
            ps += (p0v + p1v) + (p2v + p3v);
            pw[mc].x = b16(p0v); pw[mc].y = b16(p1v);
            pw[mc].z = b16(p2v); pw[mc].w = b16(p3v);
        }
        ps += __shfl_xor(ps, 16);
        ps += __shfl_xor(ps, 32);
        S += ps;

        #pragma unroll
        for (int mc = 0; mc < 4; mc++)
            *(ushort4*)&plds[w][ln][mc * 16 + lg * 4] = pw[mc];
        bf16x8 pf0 = *(const bf16x8*)&plds[w][ln][lg * 8];
        bf16x8 pf1 = *(const bf16x8*)&plds[w][ln][32 + lg * 8];

        __builtin_amdgcn_s_setprio(1);
        o0 = __builtin_amdgcn_mfma_f32_16x16x32_bf16(vf0, pf0, o0, 0, 0, 0);
        o0 = __builtin_amdgcn_mfma_f32_16x16x32_bf16(vf1, pf1, o0, 0, 0, 0);
        o1 = __builtin_amdgcn_mfma_f32_16x16x32_bf16(vf2, pf0, o1, 0, 0, 0);
        o1 = __builtin_amdgcn_mfma_f32_16x16x32_bf16(vf3, pf1, o1, 0, 0, 0);
        __builtin_amdgcn_s_setprio(0);

        if (more) {
            *(bf16x8*)&Kl[cur ^ 1][kw] = kr;
            *(bf16x8*)&Vl[cur ^ 1][vw] = vr;
        }
        cur ^= 1;
    }

    ushort* po = PO + (size_t)sp * 884736;
    #pragma unroll
    for (int r = 0; r < 4; r++) {
        const int d = lg * 4 + r;
        po[((size_t)gh * 32 + d) * HW + n0 + ln]      = b16(o0[r]);
        po[((size_t)gh * 32 + d + 16) * HW + n0 + ln] = b16(o1[r]);
    }
    if (lg == 0) {
        MS[(((size_t)sp * 12 + gh) * HW + n0 + ln) * 2] = S;
    }
}

// ---- merge 4 bf16 split-K partials + proj GEMM + residual -> CATT[ycol] ----
// fixed softmax reference: weight = 1 / sum_k S_k for all k. grid (36, 3).
__global__ __launch_bounds__(256) void merge_proj(
    const ushort* __restrict__ PO, const float* __restrict__ MS,
    const ushort* __restrict__ PW, const float* __restrict__ pb,
    ushort* __restrict__ CT, int rcol, int ycol,
    float* __restrict__ STAT, int slotAcc)
{
    __shared__ float fwv[4][64];   // [h][nl] = 1/sum S
    __shared__ __align__(16) unsigned long long obuf[64][34];
    const int g = blockIdx.y, nb = blockIdx.x * 64;
    const int t = threadIdx.x;
    {
        const int h = t >> 6, nl = t & 63, gh = g * 4 + h, n = nb + nl;
        float den = 0.f;
        #pragma unroll
        for (int k = 0; k < NSPLIT; k++)
            den += MS[(((size_t)k * 12 + gh) * HW + n) * 2];
        fwv[h][nl] = 1.f / den;
    }
    __syncthreads();
    {
        const int nl = t & 63, dd = t >> 6;
        #pragma unroll
        for (int p = 0; p < 8; p++) {
            const int d = p * 4 + dd;
            ushort uu[4];
            #pragma unroll
            for (int h = 0; h < 4; h++) {
                const int gh = g * 4 + h;
                const size_t idx = ((size_t)gh * 32 + d) * HW + nb + nl;
                float v = 0.f;
                #pragma unroll
                for (int k = 0; k < NSPLIT; k++)
                    v += bf(PO[(size_t)k * 884736 + idx]);
                uu[h] = b16(v * fwv[h][nl]);
            }
            obuf[nl][d] = (unsigned long long)uu[0] | ((unsigned long long)uu[1] << 16)
                        | ((unsigned long long)uu[2] << 32) | ((unsigned long long)uu[3] << 48);
        }
    }
    __syncthreads();
    const int w = t >> 6, l = t & 63, ln = l & 15, lg = l >> 4;
    const int wo = (w & 1) * 64, wn = (w >> 1) * 32;
    const ushort* ob_base = (const ushort*)&obuf[0][0];
    const ushort* ap = PW + (size_t)(wo + ln) * 128 + lg * 8;
    f32x4 acc[4][2];
    #pragma unroll
    for (int i = 0; i < 4; i++)
        #pragma unroll
        for (int jf = 0; jf < 2; jf++) acc[i][jf] = (f32x4){0.f, 0.f, 0.f, 0.f};
    #pragma unroll
    for (int kk = 0; kk < 4; kk++) {
        bf16x8 bfr[2];
        #pragma unroll
        for (int jf = 0; jf < 2; jf++)
            bfr[jf] = *(const bf16x8*)(ob_base + (wn + jf * 16 + ln) * 136 + kk * 32 + lg * 8);
        #pragma unroll
        for (int i = 0; i < 4; i++) {
            const bf16x8 af = *(const bf16x8*)(ap + (size_t)i * 16 * 128 + kk * 32);
            acc[i][0] = __builtin_amdgcn_mfma_f32_16x16x32_bf16(af, bfr[0], acc[i][0], 0, 0, 0);
            acc[i][1] = __builtin_amdgcn_mfma_f32_16x16x32_bf16(af, bfr[1], acc[i][1], 0, 0, 0);
        }
    }
    float ls = 0.f, lsq = 0.f;
    #pragma unroll
    for (int i = 0; i < 4; i++) {
        const int o4 = wo + i * 16 + lg * 4;
        #pragma unroll
        for (int jf = 0; jf < 2; jf++) {
            const int n = nb + wn + jf * 16 + ln;
            const size_t base = ((size_t)g * HW + n) * 512;
            ushort4 rv = *(const ushort4*)&CT[base + rcol + o4];
            float y0 = acc[i][jf][0] + pb[o4 + 0] + bf(rv.x);
            float y1 = acc[i][jf][1] + pb[o4 + 1] + bf(rv.y);
            float y2 = acc[i][jf][2] + pb[o4 + 2] + bf(rv.z);
            float y3 = acc[i][jf][3] + pb[o4 + 3] + bf(rv.w);
            ls += (y0 + y1) + (y2 + y3);
            lsq += y0 * y0 + y1 * y1 + y2 * y2 + y3 * y3;
            ushort4 u;
            u.x = b16(y0); u.y = b16(y1); u.z = b16(y2); u.w = b16(y3);
            *(ushort4*)&CT[base + ycol + o4] = u;
        }
    }
    stat_acc(STAT, slotAcc, g, ls, lsq);
}

extern "C" void kernel_launch(void* const* d_in, const int* in_sizes, int n_in,
                              void* d_out, int out_size, void* d_ws, size_t ws_size,
                              hipStream_t stream)
{
    (void)in_sizes; (void)n_in; (void)out_size; (void)ws_size;
    const float* x      = (const float*)d_in[0];
    const float* cv1_w  = (const float*)d_in[1];
    const float* cv1_g  = (const float*)d_in[2];
    const float* cv1_b  = (const float*)d_in[3];
    const float* cv1_m  = (const float*)d_in[4];
    const float* cv1_v  = (const float*)d_in[5];
    const float* n1_g   = (const float*)d_in[6];
    const float* n1_b   = (const float*)d_in[7];
    const float* qkv_w  = (const float*)d_in[8];
    const float* qkv_b  = (const float*)d_in[9];
    const float* proj_w = (const float*)d_in[10];
    const float* proj_b = (const float*)d_in[11];
    const float* n2_g   = (const float*)d_in[12];
    const float* n2_b   = (const float*)d_in[13];
    const float* f1_w   = (const float*)d_in[14];
    const float* f1_b   = (const float*)d_in[15];
    const float* f2_w   = (const float*)d_in[16];
    const float* f2_b   = (const float*)d_in[17];
    const float* cv2_w  = (const float*)d_in[18];
    const float* cv2_g  = (const float*)d_in[19];
    const float* cv2_b  = (const float*)d_in[20];
    const float* cv2_m  = (const float*)d_in[21];
    const float* cv2_v  = (const float*)d_in[22];
    float* out = (float*)d_out;

    float* ws = (float*)d_ws;
    ushort* CATT = (ushort*)ws;                      // [3][HW][512] bf16
    ushort* QT   = (ushort*)(ws + 1769472);          // [12][HW][32]
    ushort* KTb  = (ushort*)(ws + 2211840);          // [12][HW][32]
    ushort* VB   = (ushort*)(ws + 2654208);          // [384][HW]
    float*  MS   = ws + 3096576;                     // [4][12][HW][2]
    ushort* WB   = (ushort*)(ws + 3428352);          // 294912 bf16: cv1|proj|f2|cv2
    ushort* FW   = (ushort*)(ws + 3575808);          // 163840 bf16 folded qkv|f1
    float*  CV   = ws + 3657728;                     // 2560 f corrections
    float*  STAT = ws + 3660288;                     // 64 f
    ushort* XTX  = (ushort*)(ws + 3660352);          // [3][HW][256] bf16 (dead after cv1)
    ushort* PO   = (ushort*)d_out;                   // 4 x 884736 bf16 (= d_out exactly)

    dim3 blk(256);

    prep<<<dim3(1040), blk, 0, stream>>>(
        cv1_w, proj_w, f2_w, cv2_w, qkv_w, n1_g, n1_b, f1_w, n2_g, n2_b,
        x, WB, FW, CV, XTX, STAT);

    // cv1: BN+SiLU -> CATT cols 0..255; stats(slot0) over cols 128..255
    gemm_mfma<E_CV1><<<dim3(36, 4, 3), dim3(64), 0, stream>>>(
        WB + 0, XTX, 256, 256, 0, cv1_g, cv1_b, cv1_m, cv1_v,
        STAT, -1, 0, nullptr, CATT, 0, nullptr, nullptr, nullptr);

    for (int i = 0; i < 2; i++) {
        const int prev = (i == 0) ? 128 : 256;
        const int next = 256 + 128 * i;
        const int gn1 = (i == 0) ? 0 : 2;   // stats slot consumed by qkv
        const int gn2 = (i == 0) ? 1 : 3;   // stats slot consumed by ffn

        gemm_mfma<E_QKV><<<dim3(36, 6, 3), dim3(64), 0, stream>>>(
            FW + (size_t)i * 49152, CATT, 128, 512, prev, qkv_b + i * 384,
            nullptr, nullptr, nullptr, STAT, gn1, -1, CV + i * 1280,
            nullptr, 0, QT, KTb, VB);
        attn_mfma<<<dim3(36, 12, NSPLIT), blk, 0, stream>>>(QT, KTb, VB, PO, MS);
        merge_proj<<<dim3(36, 3), blk, 0, stream>>>(
            PO, MS, WB + 65536 + (size_t)i * 16384, proj_b + i * 128,
            CATT, prev, next, STAT, gn2);

        if (i == 0) {
            ffn_fused<0><<<dim3(72, 1, 3), blk, 0, stream>>>(
                FW + 98304, f1_b, CV + 768,
                WB + 98304, f2_b, CATT, 256, STAT, 1, 2,
                nullptr, nullptr, nullptr, nullptr, nullptr, nullptr);
        } else {
            ffn_fused<1><<<dim3(72, 1, 3), blk, 0, stream>>>(
                FW + 98304 + 32768, f1_b + 256, CV + 1280 + 768,
                WB + 98304 + 32768, f2_b + 128, CATT, 384, STAT, 3, -1,
                WB + 163840, cv2_g, cv2_b, cv2_m, cv2_v, out);
        }
    }
}